// Round 3
// baseline (544.941 us; speedup 1.0000x reference)
//
#include <hip/hip_runtime.h>

#define NPIX (512*512)        // 262144 pixels per channel
#define N4   (NPIX/4)         // 65536 float4 per channel
#define DIM  128
#define HALF 64
#define CHW  ((size_t)DIM*NPIX)  // 33554432 elements per tensor

typedef float v4f __attribute__((ext_vector_type(4)));

__device__ __forceinline__ void nt_store4(const float4& v, float4* p) {
    v4f x; x.x = v.x; x.y = v.y; x.z = v.z; x.w = v.w;
    __builtin_nontemporal_store(x, (v4f*)p);
}

__device__ __forceinline__ void fma4(float4& a, float s, const float4& x) {
    a.x = fmaf(s, x.x, a.x);
    a.y = fmaf(s, x.y, a.y);
    a.z = fmaf(s, x.z, a.z);
    a.w = fmaf(s, x.w, a.w);
}

// one conv input channel's contribution to this thread's 16 accumulators;
// per-acc accumulation order stays i-ascending (bit-identical to verified kernel)
__device__ __forceinline__ void conv_step(float4* acc, const float4* wT4,
                                          int i, int ty, const float4& x) {
#pragma unroll
    for (int q = 0; q < 4; ++q) {
        float4 w4 = wT4[i * 16 + ty * 4 + q];   // wave-uniform broadcast
        fma4(acc[q * 4 + 0], w4.x, x);
        fma4(acc[q * 4 + 1], w4.y, x);
        fma4(acc[q * 4 + 2], w4.z, x);
        fma4(acc[q * 4 + 3], w4.w, x);
    }
}

// ---------------- K1: per-channel means of lst and gui ----------------
__global__ __launch_bounds__(1024) void k_means(const float* __restrict__ lst,
                                                const float* __restrict__ gui,
                                                float* __restrict__ means) {
    int b = blockIdx.x;  // 0..127 = lst channels, 128..255 = gui channels
    const float* src = (b < DIM) ? (lst + (size_t)b * NPIX)
                                 : (gui + (size_t)(b - DIM) * NPIX);
    const float4* s4 = (const float4*)src;
    int t = threadIdx.x;
    float sum = 0.f;
#pragma unroll 8
    for (int k = 0; k < 64; ++k) {
        float4 v = s4[t + k * 1024];
        sum += (v.x + v.y) + (v.z + v.w);
    }
    for (int off = 32; off > 0; off >>= 1)
        sum += __shfl_down(sum, off, 64);
    __shared__ float red[16];
    int wave = t >> 6, lane = t & 63;
    if (lane == 0) red[wave] = sum;
    __syncthreads();
    if (t == 0) {
        float tot = 0.f;
        for (int w = 0; w < 16; ++w) tot += red[w];
        means[b] = tot * (1.0f / (float)NPIX);
    }
}

// ------- K2: per-block redundant select + channel exchange + passthrough -------
// Selection (tiny MLPs + top-64) is recomputed in every block from means[]:
// ~0.2us of serial FMA per block, all weight reads L2-hot. This removes the
// 1-block k_select launch that idled 255 CUs, and one launch gap.
__global__ __launch_bounds__(256) void k_fused(
    const float* __restrict__ lst, const float* __restrict__ gui,
    const float* __restrict__ mask,
    const float* __restrict__ w1, const float* __restrict__ b1,
    const float* __restrict__ w2, const float* __restrict__ b2,
    const float* __restrict__ se_w1, const float* __restrict__ se_b1,
    const float* __restrict__ se_w2, const float* __restrict__ se_b2,
    const float* __restrict__ c1w, const float* __restrict__ c1b,
    const float* __restrict__ c2w, const float* __restrict__ c2b,
    const float* __restrict__ means,
    float* __restrict__ out)
{
    int t = threadIdx.x;
    int z = blockIdx.y;

    __shared__ float wT[HALF * HALF];   // wT[i*64 + o] = w[o*64 + i]
    __shared__ float bs[HALF];
    __shared__ int   sidx[HALF], suidx[HALF];
    __shared__ float spooled[256], smask[64], h[128], se1[16], mv[128];
    __shared__ int   ssel[128];

    // stage transposed conv weights + bias early (loads overlap select MLP)
    {
        const float* w    = (z == 0) ? c2w : c1w;
        const float* bias = (z == 0) ? c2b : c1b;
        for (int k2 = t; k2 < HALF * HALF; k2 += 256) {
            int o = k2 >> 6, i = k2 & 63;
            wT[i * HALF + o] = w[k2];
        }
        if (t < HALF) bs[t] = bias[t];
    }

    // ---------- selection (arithmetic identical to verified k_select) ----------
    if (t < 64) smask[t] = mask[t];
    spooled[t] = means[t];                 // t in 0..255 covers all 256 means
    __syncthreads();

    if (t < 128) {
        float a = b1[t];
        for (int i = 0; i < 64; ++i) a = fmaf(smask[i], w1[i * DIM + t], a);
        h[t] = fmaxf(a, 0.f);
    }
    __syncthreads();

    float m1 = 0.f;
    if (t < 128) {
        float a2 = b2[t];
        for (int i = 0; i < 128; ++i) a2 = fmaf(h[i], w2[i * DIM + t], a2);
        m1 = 1.f / (1.f + expf(-a2));
    }
    if (t < 16) {
        float bb = se_b1[t];
        for (int i = 0; i < 256; ++i) bb = fmaf(spooled[i], se_w1[i * 16 + t], bb);
        se1[t] = fmaxf(bb, 0.f);
    }
    __syncthreads();

    if (t < 128) {
        float a3 = se_b2[t];
        for (int i = 0; i < 16; ++i) a3 = fmaf(se1[i], se_w2[i * DIM + t], a3);
        float m2 = 1.f / (1.f + expf(-a3));
        float mval = m1 * m2;
        mv[t] = mval;
        if (blockIdx.x == 0 && z == 0) out[2 * CHW + t] = mval;   // m output
    }
    __syncthreads();

    if (t < 128) {
        float mval = mv[t];
        int rank = 0;
        for (int i = 0; i < 128; ++i) {
            float o = mv[i];
            rank += (o > mval) || (o == mval && i < t);
        }
        ssel[t] = (rank < HALF) ? 1 : 0;
    }
    __syncthreads();
    if (t < 128) {
        int pos = 0;
        for (int i = 0; i < t; ++i) pos += ssel[i];
        if (ssel[t]) sidx[pos] = t;          // ascending channel order
        else         suidx[t - pos] = t;     // ascending complement
    }
    __syncthreads();

    // ---------- exchange + passthrough ----------
    // z==0: out_lst <- conv2_w @ gui[idx] + conv2_b ; copy unselected lst
    // z==1: out_gui <- conv1_w @ lst[idx] + conv1_b ; copy unselected gui
    const float4* conv_src = (const float4*)((z == 0) ? gui : lst);
    const float4* copy_src = (const float4*)((z == 0) ? lst : gui);
    float4* dst4 = (float4*)(out + (size_t)z * CHW);
    const float4* wT4 = (const float4*)wT;

    int tx = t & 63;          // pixel group (coalescing dim)
    int ty = t >> 6;          // 0..3 output-channel quarter
    int jbase = ty * 16;
    int p4 = blockIdx.x * 64 + tx;   // float4 index within a channel

    float4 acc[16];
#pragma unroll
    for (int j = 0; j < 16; ++j) {
        float bv = bs[jbase + j];
        acc[j] = make_float4(bv, bv, bv, bv);
    }

    // conv over the 64 selected input channels, 4 loads in flight
#pragma unroll 2
    for (int i0 = 0; i0 < HALF; i0 += 4) {
        float4 x0 = conv_src[(size_t)sidx[i0 + 0] * N4 + p4];
        float4 x1 = conv_src[(size_t)sidx[i0 + 1] * N4 + p4];
        float4 x2 = conv_src[(size_t)sidx[i0 + 2] * N4 + p4];
        float4 x3 = conv_src[(size_t)sidx[i0 + 3] * N4 + p4];
        conv_step(acc, wT4, i0 + 0, ty, x0);
        conv_step(acc, wT4, i0 + 1, ty, x1);
        conv_step(acc, wT4, i0 + 2, ty, x2);
        conv_step(acc, wT4, i0 + 3, ty, x3);
    }

    // conv results -> selected channels
#pragma unroll
    for (int j = 0; j < 16; ++j) {
        int c = sidx[jbase + j];
        nt_store4(acc[j], &dst4[(size_t)c * N4 + p4]);
    }

    // passthrough -> unselected channels (each wave owns 16 of the 64),
    // staged through registers in batches of 8 so loads overlap
#pragma unroll
    for (int rr = 0; rr < 2; ++rr) {
        float4 v[8];
#pragma unroll
        for (int j = 0; j < 8; ++j)
            v[j] = copy_src[(size_t)suidx[jbase + rr * 8 + j] * N4 + p4];
#pragma unroll
        for (int j = 0; j < 8; ++j)
            nt_store4(v[j], &dst4[(size_t)suidx[jbase + rr * 8 + j] * N4 + p4]);
    }
}

extern "C" void kernel_launch(void* const* d_in, const int* in_sizes, int n_in,
                              void* d_out, int out_size, void* d_ws, size_t ws_size,
                              hipStream_t stream) {
    const float* lst   = (const float*)d_in[0];
    const float* gui   = (const float*)d_in[1];
    const float* mask  = (const float*)d_in[2];
    const float* w1    = (const float*)d_in[3];
    const float* b1    = (const float*)d_in[4];
    const float* w2    = (const float*)d_in[5];
    const float* b2    = (const float*)d_in[6];
    const float* se_w1 = (const float*)d_in[7];
    const float* se_b1 = (const float*)d_in[8];
    const float* se_w2 = (const float*)d_in[9];
    const float* se_b2 = (const float*)d_in[10];
    const float* c1w   = (const float*)d_in[11];
    const float* c1b   = (const float*)d_in[12];
    const float* c2w   = (const float*)d_in[13];
    const float* c2b   = (const float*)d_in[14];
    float* out = (float*)d_out;
    float* means = (float*)d_ws;   // 256 floats

    k_means<<<dim3(256), dim3(1024), 0, stream>>>(lst, gui, means);
    k_fused<<<dim3(NPIX / 256, 2), dim3(256), 0, stream>>>(
        lst, gui, mask, w1, b1, w2, b2, se_w1, se_b1, se_w2, se_b2,
        c1w, c1b, c2w, c2b, means, out);
}

// Round 6
// 538.471 us; speedup vs baseline: 1.0120x; 1.0120x over previous
//
#include <hip/hip_runtime.h>

#define NPIX (512*512)        // 262144 pixels per channel
#define N4   (NPIX/4)         // 65536 float4 per channel
#define DIM  128
#define HALF 64
#define CHW  ((size_t)DIM*NPIX)  // 33554432 elements per tensor

typedef float v4f __attribute__((ext_vector_type(4)));

__device__ __forceinline__ void nt_store4(const float4& v, float4* p) {
    v4f x; x.x = v.x; x.y = v.y; x.z = v.z; x.w = v.w;
    __builtin_nontemporal_store(x, (v4f*)p);
}

__device__ __forceinline__ void fma4(float4& a, float s, const float4& x) {
    a.x = fmaf(s, x.x, a.x);
    a.y = fmaf(s, x.y, a.y);
    a.z = fmaf(s, x.z, a.z);
    a.w = fmaf(s, x.w, a.w);
}

// one conv input channel's contribution to this thread's 16 accumulators;
// per-acc accumulation order stays i-ascending (bit-identical results)
__device__ __forceinline__ void conv_step(float4* acc, const float4* wT4,
                                          int i, int ty, const float4& x) {
#pragma unroll
    for (int q = 0; q < 4; ++q) {
        float4 w4 = wT4[i * 16 + ty * 4 + q];   // wave-uniform broadcast
        fma4(acc[q * 4 + 0], w4.x, x);
        fma4(acc[q * 4 + 1], w4.y, x);
        fma4(acc[q * 4 + 2], w4.z, x);
        fma4(acc[q * 4 + 3], w4.w, x);
    }
}

// ---------------- K1: per-channel means of lst and gui ----------------
__global__ __launch_bounds__(1024) void k_means(const float* __restrict__ lst,
                                                const float* __restrict__ gui,
                                                float* __restrict__ means) {
    int b = blockIdx.x;  // 0..127 = lst channels, 128..255 = gui channels
    const float* src = (b < DIM) ? (lst + (size_t)b * NPIX)
                                 : (gui + (size_t)(b - DIM) * NPIX);
    const float4* s4 = (const float4*)src;
    int t = threadIdx.x;
    float sum = 0.f;
#pragma unroll 8
    for (int k = 0; k < 64; ++k) {
        float4 v = s4[t + k * 1024];
        sum += (v.x + v.y) + (v.z + v.w);
    }
    for (int off = 32; off > 0; off >>= 1)
        sum += __shfl_down(sum, off, 64);
    __shared__ float red[16];
    int wave = t >> 6, lane = t & 63;
    if (lane == 0) red[wave] = sum;
    __syncthreads();
    if (t == 0) {
        float tot = 0.f;
        for (int w = 0; w < 16; ++w) tot += red[w];
        means[b] = tot * (1.0f / (float)NPIX);
    }
}

// ---------------- K2: MLPs + sigmoid + top-64 selection ----------------
__global__ __launch_bounds__(128) void k_select(
    const float* __restrict__ mask, const float* __restrict__ w1, const float* __restrict__ b1,
    const float* __restrict__ w2, const float* __restrict__ b2,
    const float* __restrict__ se_w1, const float* __restrict__ se_b1,
    const float* __restrict__ se_w2, const float* __restrict__ se_b2,
    const float* __restrict__ means,
    float* __restrict__ m_out, int* __restrict__ idx_out, int* __restrict__ uidx_out)
{
    int t = threadIdx.x;  // 0..127
    __shared__ float smask[64], h[128], pooled[256], se1[16], mv[128];
    __shared__ int sel[128];

    if (t < 64) smask[t] = mask[t];
    pooled[t]       = means[t];
    pooled[t + 128] = means[t + 128];
    __syncthreads();

    // h = relu(mask @ w1 + b1)   w1: [64,128] row-major
    float a = b1[t];
    for (int i = 0; i < 64; ++i) a = fmaf(smask[i], w1[i * DIM + t], a);
    h[t] = fmaxf(a, 0.f);
    __syncthreads();

    // mask1 = sigmoid(h @ w2 + b2)   w2: [128,128]
    float a2 = b2[t];
    for (int i = 0; i < 128; ++i) a2 = fmaf(h[i], w2[i * DIM + t], a2);
    float m1 = 1.f / (1.f + expf(-a2));

    // SE: se1 = relu(pooled @ se_w1 + se_b1)   se_w1: [256,16]
    if (t < 16) {
        float b = se_b1[t];
        for (int i = 0; i < 256; ++i) b = fmaf(pooled[i], se_w1[i * 16 + t], b);
        se1[t] = fmaxf(b, 0.f);
    }
    __syncthreads();

    // mask2 = sigmoid(se1 @ se_w2 + se_b2)   se_w2: [16,128]
    float a3 = se_b2[t];
    for (int i = 0; i < 16; ++i) a3 = fmaf(se1[i], se_w2[i * DIM + t], a3);
    float m2 = 1.f / (1.f + expf(-a3));

    float mval = m1 * m2;
    mv[t] = mval;
    m_out[t] = mval;
    __syncthreads();

    // stable top-64: rank = #(strictly greater) + #(equal with smaller index)
    int rank = 0;
    for (int i = 0; i < 128; ++i) {
        float o = mv[i];
        rank += (o > mval) || (o == mval && i < t);
    }
    int is_sel = (rank < HALF) ? 1 : 0;
    sel[t] = is_sel;
    __syncthreads();
    int pos = 0;
    for (int i = 0; i < t; ++i) pos += sel[i];
    if (is_sel) idx_out[pos] = t;          // ascending channel order
    else        uidx_out[t - pos] = t;     // ascending complement
}

// ---------------- K3: fused channel exchange + passthrough ----------------
// Round-1 verified kernel + 4-wide conv load batching (the one clean,
// previously-confounded micro-opt): 4 global loads in flight per wave
// instead of 2 before their FMA groups. Accumulation order unchanged.
__global__ __launch_bounds__(256) void k_fused(
    const float* __restrict__ lst, const float* __restrict__ gui,
    const float* __restrict__ c1w, const float* __restrict__ c1b,
    const float* __restrict__ c2w, const float* __restrict__ c2b,
    const int* __restrict__ idx, const int* __restrict__ uidx,
    float* __restrict__ out)
{
    // z==0: out_lst <- conv2_w @ gui[idx] + conv2_b ; copy unselected lst
    // z==1: out_gui <- conv1_w @ lst[idx] + conv1_b ; copy unselected gui
    int z = blockIdx.y;
    const float* w    = (z == 0) ? c2w : c1w;
    const float* bias = (z == 0) ? c2b : c1b;
    const float4* conv_src = (const float4*)((z == 0) ? gui : lst);
    const float4* copy_src = (const float4*)((z == 0) ? lst : gui);
    float4* dst4 = (float4*)(out + (size_t)z * CHW);

    __shared__ float wT[HALF * HALF];   // wT[i*64 + o] = w[o*64 + i]
    __shared__ float bs[HALF];
    __shared__ int idxs[HALF];
    __shared__ int uidxs[HALF];
    int tid = threadIdx.x;
    for (int k = tid; k < HALF * HALF; k += 256) {
        int o = k >> 6, i = k & 63;
        wT[i * HALF + o] = w[k];
    }
    if (tid < HALF) { bs[tid] = bias[tid]; idxs[tid] = idx[tid]; uidxs[tid] = uidx[tid]; }
    __syncthreads();

    int tx = tid & 63;          // pixel group within block (coalescing dim)
    int ty = tid >> 6;          // 0..3 output-channel quarter
    int jbase = ty * 16;
    int p4 = blockIdx.x * 64 + tx;   // float4 index within a channel

    const float4* wT4 = (const float4*)wT;

    float4 acc[16];
#pragma unroll
    for (int j = 0; j < 16; ++j) {
        float b = bs[jbase + j];
        acc[j] = make_float4(b, b, b, b);
    }

    // conv over the 64 selected input channels, 4 loads in flight
#pragma unroll 2
    for (int i0 = 0; i0 < HALF; i0 += 4) {
        float4 x0 = conv_src[(size_t)idxs[i0 + 0] * N4 + p4];
        float4 x1 = conv_src[(size_t)idxs[i0 + 1] * N4 + p4];
        float4 x2 = conv_src[(size_t)idxs[i0 + 2] * N4 + p4];
        float4 x3 = conv_src[(size_t)idxs[i0 + 3] * N4 + p4];
        conv_step(acc, wT4, i0 + 0, ty, x0);
        conv_step(acc, wT4, i0 + 1, ty, x1);
        conv_step(acc, wT4, i0 + 2, ty, x2);
        conv_step(acc, wT4, i0 + 3, ty, x3);
    }

    // conv results -> selected channels
#pragma unroll
    for (int j = 0; j < 16; ++j) {
        int c = idxs[jbase + j];
        nt_store4(acc[j], &dst4[(size_t)c * N4 + p4]);
    }

    // passthrough -> unselected channels (each wave owns 16 of the 64),
    // staged through registers in batches of 8 so loads overlap
#pragma unroll
    for (int r = 0; r < 2; ++r) {
        float4 v[8];
#pragma unroll
        for (int j = 0; j < 8; ++j)
            v[j] = copy_src[(size_t)uidxs[jbase + r * 8 + j] * N4 + p4];
#pragma unroll
        for (int j = 0; j < 8; ++j)
            nt_store4(v[j], &dst4[(size_t)uidxs[jbase + r * 8 + j] * N4 + p4]);
    }
}

extern "C" void kernel_launch(void* const* d_in, const int* in_sizes, int n_in,
                              void* d_out, int out_size, void* d_ws, size_t ws_size,
                              hipStream_t stream) {
    const float* lst   = (const float*)d_in[0];
    const float* gui   = (const float*)d_in[1];
    const float* mask  = (const float*)d_in[2];
    const float* w1    = (const float*)d_in[3];
    const float* b1    = (const float*)d_in[4];
    const float* w2    = (const float*)d_in[5];
    const float* b2    = (const float*)d_in[6];
    const float* se_w1 = (const float*)d_in[7];
    const float* se_b1 = (const float*)d_in[8];
    const float* se_w2 = (const float*)d_in[9];
    const float* se_b2 = (const float*)d_in[10];
    const float* c1w   = (const float*)d_in[11];
    const float* c1b   = (const float*)d_in[12];
    const float* c2w   = (const float*)d_in[13];
    const float* c2b   = (const float*)d_in[14];
    float* out = (float*)d_out;

    float* means = (float*)d_ws;                        // 256 floats
    int* idx     = (int*)((char*)d_ws + 1024);          // 64 ints
    int* uidx    = (int*)((char*)d_ws + 1024 + 256);    // 64 ints

    k_means<<<dim3(256), dim3(1024), 0, stream>>>(lst, gui, means);
    k_select<<<dim3(1), dim3(128), 0, stream>>>(mask, w1, b1, w2, b2,
                                                se_w1, se_b1, se_w2, se_b2,
                                                means, out + 2 * CHW, idx, uidx);
    k_fused<<<dim3(NPIX / 256, 2), dim3(256), 0, stream>>>(lst, gui, c1w, c1b, c2w, c2b,
                                                           idx, uidx, out);
}

// Round 7
// 533.864 us; speedup vs baseline: 1.0207x; 1.0086x over previous
//
#include <hip/hip_runtime.h>

#define NPIX (512*512)        // 262144 pixels per channel
#define N4   (NPIX/4)         // 65536 float4 per channel
#define DIM  128
#define HALF 64
#define BK   4                // conv channels staged per step
#define CHW  ((size_t)DIM*NPIX)  // 33554432 elements per tensor

typedef float v4f __attribute__((ext_vector_type(4)));

__device__ __forceinline__ void nt_store4(const float4& v, float4* p) {
    v4f x; x.x = v.x; x.y = v.y; x.z = v.z; x.w = v.w;
    __builtin_nontemporal_store(x, (v4f*)p);
}

__device__ __forceinline__ void fma4(float4& a, float s, const float4& x) {
    a.x = fmaf(s, x.x, a.x);
    a.y = fmaf(s, x.y, a.y);
    a.z = fmaf(s, x.z, a.z);
    a.w = fmaf(s, x.w, a.w);
}

// one conv input channel's contribution to this thread's 16 accumulators;
// per-acc accumulation order stays channel-ascending (bit-identical results)
__device__ __forceinline__ void conv_step(float4* acc, const float4* wT4,
                                          int i, int ty, const float4& x) {
#pragma unroll
    for (int q = 0; q < 4; ++q) {
        float4 w4 = wT4[i * 16 + ty * 4 + q];   // wave-uniform broadcast
        fma4(acc[q * 4 + 0], w4.x, x);
        fma4(acc[q * 4 + 1], w4.y, x);
        fma4(acc[q * 4 + 2], w4.z, x);
        fma4(acc[q * 4 + 3], w4.w, x);
    }
}

// ---------------- K1: per-channel means of lst and gui ----------------
__global__ __launch_bounds__(1024) void k_means(const float* __restrict__ lst,
                                                const float* __restrict__ gui,
                                                float* __restrict__ means) {
    int b = blockIdx.x;  // 0..127 = lst channels, 128..255 = gui channels
    const float* src = (b < DIM) ? (lst + (size_t)b * NPIX)
                                 : (gui + (size_t)(b - DIM) * NPIX);
    const float4* s4 = (const float4*)src;
    int t = threadIdx.x;
    float sum = 0.f;
#pragma unroll 8
    for (int k = 0; k < 64; ++k) {
        float4 v = s4[t + k * 1024];
        sum += (v.x + v.y) + (v.z + v.w);
    }
    for (int off = 32; off > 0; off >>= 1)
        sum += __shfl_down(sum, off, 64);
    __shared__ float red[16];
    int wave = t >> 6, lane = t & 63;
    if (lane == 0) red[wave] = sum;
    __syncthreads();
    if (t == 0) {
        float tot = 0.f;
        for (int w = 0; w < 16; ++w) tot += red[w];
        means[b] = tot * (1.0f / (float)NPIX);
    }
}

// ---------------- K2: MLPs + sigmoid + top-64 selection ----------------
__global__ __launch_bounds__(128) void k_select(
    const float* __restrict__ mask, const float* __restrict__ w1, const float* __restrict__ b1,
    const float* __restrict__ w2, const float* __restrict__ b2,
    const float* __restrict__ se_w1, const float* __restrict__ se_b1,
    const float* __restrict__ se_w2, const float* __restrict__ se_b2,
    const float* __restrict__ means,
    float* __restrict__ m_out, int* __restrict__ idx_out, int* __restrict__ uidx_out)
{
    int t = threadIdx.x;  // 0..127
    __shared__ float smask[64], h[128], pooled[256], se1[16], mv[128];
    __shared__ int sel[128];

    if (t < 64) smask[t] = mask[t];
    pooled[t]       = means[t];
    pooled[t + 128] = means[t + 128];
    __syncthreads();

    // h = relu(mask @ w1 + b1)   w1: [64,128] row-major
    float a = b1[t];
    for (int i = 0; i < 64; ++i) a = fmaf(smask[i], w1[i * DIM + t], a);
    h[t] = fmaxf(a, 0.f);
    __syncthreads();

    // mask1 = sigmoid(h @ w2 + b2)   w2: [128,128]
    float a2 = b2[t];
    for (int i = 0; i < 128; ++i) a2 = fmaf(h[i], w2[i * DIM + t], a2);
    float m1 = 1.f / (1.f + expf(-a2));

    // SE: se1 = relu(pooled @ se_w1 + se_b1)   se_w1: [256,16]
    if (t < 16) {
        float b = se_b1[t];
        for (int i = 0; i < 256; ++i) b = fmaf(pooled[i], se_w1[i * 16 + t], b);
        se1[t] = fmaxf(b, 0.f);
    }
    __syncthreads();

    // mask2 = sigmoid(se1 @ se_w2 + se_b2)   se_w2: [16,128]
    float a3 = se_b2[t];
    for (int i = 0; i < 16; ++i) a3 = fmaf(se1[i], se_w2[i * DIM + t], a3);
    float m2 = 1.f / (1.f + expf(-a3));

    float mval = m1 * m2;
    mv[t] = mval;
    m_out[t] = mval;
    __syncthreads();

    // stable top-64: rank = #(strictly greater) + #(equal with smaller index)
    int rank = 0;
    for (int i = 0; i < 128; ++i) {
        float o = mv[i];
        rank += (o > mval) || (o == mval && i < t);
    }
    int is_sel = (rank < HALF) ? 1 : 0;
    sel[t] = is_sel;
    __syncthreads();
    int pos = 0;
    for (int i = 0; i < t; ++i) pos += sel[i];
    if (is_sel) idx_out[pos] = t;          // ascending channel order
    else        uidx_out[t - pos] = t;     // ascending complement
}

// ---------------- K3: fused channel exchange + passthrough ----------------
// This round: conv input staged through LDS (double-buffered, BK=4 channels
// per step). Previously all 4 waves of a block loaded the SAME x-line from
// global (4x redundant issue -> L1/L2 thrash across drifting waves). Now
// wave ty stages channel idxs[s*4+ty] once; all waves consume from LDS.
// Staging load is issued BEFORE the compute step, LDS-written after
// (issue-early / write-late), so HBM latency hides under the 256-FMA step.
// FMA order stays absolute-channel-ascending -> bit-exact output.
__global__ __launch_bounds__(256) void k_fused(
    const float* __restrict__ lst, const float* __restrict__ gui,
    const float* __restrict__ c1w, const float* __restrict__ c1b,
    const float* __restrict__ c2w, const float* __restrict__ c2b,
    const int* __restrict__ idx, const int* __restrict__ uidx,
    float* __restrict__ out)
{
    // z==0: out_lst <- conv2_w @ gui[idx] + conv2_b ; copy unselected lst
    // z==1: out_gui <- conv1_w @ lst[idx] + conv1_b ; copy unselected gui
    int z = blockIdx.y;
    const float* w    = (z == 0) ? c2w : c1w;
    const float* bias = (z == 0) ? c2b : c1b;
    const float4* conv_src = (const float4*)((z == 0) ? gui : lst);
    const float4* copy_src = (const float4*)((z == 0) ? lst : gui);
    float4* dst4 = (float4*)(out + (size_t)z * CHW);

    __shared__ float wT[HALF * HALF];     // wT[i*64 + o] = w[o*64 + i] (16 KB)
    __shared__ float bs[HALF];
    __shared__ int idxs[HALF];
    __shared__ int uidxs[HALF];
    __shared__ float4 xs[2][BK][64];      // staged conv input (8 KB)

    int tid = threadIdx.x;
    for (int k = tid; k < HALF * HALF; k += 256) {
        int o = k >> 6, i = k & 63;
        wT[i * HALF + o] = w[k];
    }
    if (tid < HALF) { bs[tid] = bias[tid]; idxs[tid] = idx[tid]; uidxs[tid] = uidx[tid]; }
    __syncthreads();

    int tx = tid & 63;          // pixel group within block (coalescing dim)
    int ty = tid >> 6;          // 0..3 output-channel quarter / staging channel
    int jbase = ty * 16;
    int p4 = blockIdx.x * 64 + tx;   // float4 index within a channel

    const float4* wT4 = (const float4*)wT;

    float4 acc[16];
#pragma unroll
    for (int j = 0; j < 16; ++j) {
        float b = bs[jbase + j];
        acc[j] = make_float4(b, b, b, b);
    }

    // prologue: stage channels 0..3 (wave ty loads channel ty's 64 float4)
    xs[0][ty][tx] = conv_src[(size_t)idxs[ty] * N4 + p4];
    __syncthreads();

    // 16 steps x BK=4 channels, double-buffered
#pragma unroll 1
    for (int s = 0; s < 16; ++s) {
        int buf = s & 1;
        float4 nxt;
        if (s < 15)   // issue next-step load early; consumed after compute
            nxt = conv_src[(size_t)idxs[(s + 1) * BK + ty] * N4 + p4];
#pragma unroll
        for (int i = 0; i < BK; ++i) {
            float4 x = xs[buf][i][tx];
            conv_step(acc, wT4, s * BK + i, ty, x);
        }
        if (s < 15)   // write-late into the other buffer (readers done at prev barrier)
            xs[buf ^ 1][ty][tx] = nxt;
        __syncthreads();
    }

    // conv results -> selected channels
#pragma unroll
    for (int j = 0; j < 16; ++j) {
        int c = idxs[jbase + j];
        nt_store4(acc[j], &dst4[(size_t)c * N4 + p4]);
    }

    // passthrough -> unselected channels (each wave owns 16 of the 64),
    // staged through registers in batches of 8 so loads overlap
#pragma unroll
    for (int r = 0; r < 2; ++r) {
        float4 v[8];
#pragma unroll
        for (int j = 0; j < 8; ++j)
            v[j] = copy_src[(size_t)uidxs[jbase + r * 8 + j] * N4 + p4];
#pragma unroll
        for (int j = 0; j < 8; ++j)
            nt_store4(v[j], &dst4[(size_t)uidxs[jbase + r * 8 + j] * N4 + p4]);
    }
}

extern "C" void kernel_launch(void* const* d_in, const int* in_sizes, int n_in,
                              void* d_out, int out_size, void* d_ws, size_t ws_size,
                              hipStream_t stream) {
    const float* lst   = (const float*)d_in[0];
    const float* gui   = (const float*)d_in[1];
    const float* mask  = (const float*)d_in[2];
    const float* w1    = (const float*)d_in[3];
    const float* b1    = (const float*)d_in[4];
    const float* w2    = (const float*)d_in[5];
    const float* b2    = (const float*)d_in[6];
    const float* se_w1 = (const float*)d_in[7];
    const float* se_b1 = (const float*)d_in[8];
    const float* se_w2 = (const float*)d_in[9];
    const float* se_b2 = (const float*)d_in[10];
    const float* c1w   = (const float*)d_in[11];
    const float* c1b   = (const float*)d_in[12];
    const float* c2w   = (const float*)d_in[13];
    const float* c2b   = (const float*)d_in[14];
    float* out = (float*)d_out;

    float* means = (float*)d_ws;                        // 256 floats
    int* idx     = (int*)((char*)d_ws + 1024);          // 64 ints
    int* uidx    = (int*)((char*)d_ws + 1024 + 256);    // 64 ints

    k_means<<<dim3(256), dim3(1024), 0, stream>>>(lst, gui, means);
    k_select<<<dim3(1), dim3(128), 0, stream>>>(mask, w1, b1, w2, b2,
                                                se_w1, se_b1, se_w2, se_b2,
                                                means, out + 2 * CHW, idx, uidx);
    k_fused<<<dim3(NPIX / 256, 2), dim3(256), 0, stream>>>(lst, gui, c1w, c1b, c2w, c2b,
                                                           idx, uidx, out);
}